// Round 10
// baseline (270.961 us; speedup 1.0000x reference)
//
#include <hip/hip_runtime.h>
#include <hip/hip_bf16.h>

#define E_N 640000
#define N_N 40000
#define SCAN_B 157  // ceil(40000/256)

typedef __attribute__((ext_vector_type(8))) short short8;
typedef __attribute__((ext_vector_type(4))) float f32x4;

static __device__ __forceinline__ unsigned short f2bf(float f) {
  __hip_bfloat16 h = __float2bfloat16(f);
  unsigned short u;
  __builtin_memcpy(&u, &h, 2);
  return u;
}
static __device__ __forceinline__ float bf2f(unsigned short u) {
  return __uint_as_float(((unsigned int)u) << 16);
}

// ---------------- Wt[layer][k][o][i] = bf16(W[k][i][o]), both layers in one dispatch ----------------
__global__ __launch_bounds__(256) void wtrans_kernel(
    const float* __restrict__ W1, const float* __restrict__ W2,
    unsigned short* __restrict__ Wt) {  // Wt: [2][25][64][64]
  int t = blockIdx.x * 256 + threadIdx.x;  // 0..204799
  int half = t >= 102400;
  int r = t - (half ? 102400 : 0);
  const float* W = half ? W2 : W1;
  int k = r >> 12, rr = r & 4095, o = rr >> 6, i = rr & 63;
  Wt[((size_t)half * 102400) + (k << 12) + (o << 6) + i] = f2bf(W[(k << 12) + (i << 6) + o]);
}

// ---------------- Y[n,k,o] via MFMA: C[o][node] = Wt_rows x x_cols ----------------
// writeout staged through wave-private LDS so every global store instruction
// covers full 128B cache lines (kills L2 write-allocate RMW fetch of Y)
__global__ __launch_bounds__(256) void ygemm_kernel(
    const float* __restrict__ x, const unsigned short* __restrict__ Wt,
    unsigned short* __restrict__ Y) {
  __shared__ unsigned short tile[4][64 * 72];  // stride 144B (16B-aligned)
  const int n0 = blockIdx.x * 64;
  const int w = threadIdx.x >> 6;
  const int l = threadIdx.x & 63;
  const int lr = l & 15;
  const int lh = l >> 4;
  unsigned short* tl = tile[w];

  short8 bx[4][2];
  #pragma unroll
  for (int nt = 0; nt < 4; ++nt) {
    const float* xp = x + ((size_t)(n0 + nt * 16 + lr) << 6) + (lh << 3);
    #pragma unroll
    for (int h = 0; h < 2; ++h) {
      float4 lo = *(const float4*)(xp + h * 32);
      float4 hi = *(const float4*)(xp + h * 32 + 4);
      short8 b;
      b[0] = (short)f2bf(lo.x); b[1] = (short)f2bf(lo.y);
      b[2] = (short)f2bf(lo.z); b[3] = (short)f2bf(lo.w);
      b[4] = (short)f2bf(hi.x); b[5] = (short)f2bf(hi.y);
      b[6] = (short)f2bf(hi.z); b[7] = (short)f2bf(hi.w);
      bx[nt][h] = b;
    }
  }

  const f32x4 Z = {0.0f, 0.0f, 0.0f, 0.0f};

  for (int k = w; k < 25; k += 4) {
    const unsigned short* wk = Wt + ((size_t)k << 12);
    short8 aw[4][2];
    #pragma unroll
    for (int ot = 0; ot < 4; ++ot)
      #pragma unroll
      for (int h = 0; h < 2; ++h)
        aw[ot][h] = *(const short8*)(wk + ((ot * 16 + lr) << 6) + (h << 5) + (lh << 3));

    f32x4 acc[4][4];
    #pragma unroll
    for (int ot = 0; ot < 4; ++ot)
      #pragma unroll
      for (int nt = 0; nt < 4; ++nt) {
        acc[ot][nt] = __builtin_amdgcn_mfma_f32_16x16x32_bf16(aw[ot][0], bx[nt][0], Z, 0, 0, 0);
        acc[ot][nt] = __builtin_amdgcn_mfma_f32_16x16x32_bf16(aw[ot][1], bx[nt][1], acc[ot][nt], 0, 0, 0);
      }

    // pack C into per-wave LDS tile [node][o], row stride 72 shorts
    #pragma unroll
    for (int ot = 0; ot < 4; ++ot)
      #pragma unroll
      for (int nt = 0; nt < 4; ++nt) {
        int node = nt * 16 + lr;
        int o = ot * 16 + (lh << 2);
        uint2 p;
        p.x = (unsigned)f2bf(acc[ot][nt][0]) | ((unsigned)f2bf(acc[ot][nt][1]) << 16);
        p.y = (unsigned)f2bf(acc[ot][nt][2]) | ((unsigned)f2bf(acc[ot][nt][3]) << 16);
        *(uint2*)(tl + node * 72 + o) = p;
      }

    // copy out: each instruction writes 8 complete 128B lines
    #pragma unroll
    for (int r8 = 0; r8 < 8; ++r8) {
      int node = r8 * 8 + (l >> 3);
      int c = (l & 7) << 3;  // o offset in shorts, 16B chunk
      uint4 v = *(const uint4*)(tl + node * 72 + c);
      *(uint4*)(Y + ((size_t)(n0 + node) * 25 + k) * 64 + c) = v;
    }
  }
}

// ---------------- CSR build: histogram -> 3-stage parallel scan -> scatter ----------------
__global__ __launch_bounds__(256) void hist_kernel(
    const int* __restrict__ ei, int* __restrict__ cnt) {
  int e = blockIdx.x * 256 + threadIdx.x;
  atomicAdd(&cnt[ei[E_N + e]], 1);
}

__global__ __launch_bounds__(256) void scan1_kernel(
    const int* __restrict__ cnt, int* __restrict__ bsum) {
  __shared__ int red[256];
  int t = threadIdx.x;
  int j = blockIdx.x * 256 + t;
  red[t] = (j < N_N) ? cnt[j] : 0;
  __syncthreads();
  #pragma unroll
  for (int s = 128; s > 0; s >>= 1) {
    if (t < s) red[t] += red[t + s];
    __syncthreads();
  }
  if (t == 0) bsum[blockIdx.x] = red[0];
}

__global__ __launch_bounds__(256) void scan2_kernel(
    const int* __restrict__ bsum, int* __restrict__ bofs) {
  __shared__ int v[256];
  int t = threadIdx.x;
  v[t] = (t < SCAN_B) ? bsum[t] : 0;
  __syncthreads();
  if (t == 0) {
    int acc = 0;
    for (int i = 0; i < SCAN_B; ++i) { int c = v[i]; v[i] = acc; acc += c; }
  }
  __syncthreads();
  if (t < SCAN_B) bofs[t] = v[t];
}

__global__ __launch_bounds__(256) void scan3_kernel(
    int* __restrict__ cnt, const int* __restrict__ bofs,
    int* __restrict__ start) {
  __shared__ int v[2][256];
  int t = threadIdx.x;
  int j = blockIdx.x * 256 + t;
  int c = (j < N_N) ? cnt[j] : 0;
  v[0][t] = c;
  __syncthreads();
  int cur = 0;
  #pragma unroll
  for (int s = 1; s < 256; s <<= 1) {
    v[1 - cur][t] = (t >= s) ? v[cur][t] + v[cur][t - s] : v[cur][t];
    __syncthreads();
    cur = 1 - cur;
  }
  if (j < N_N) {
    int ex = bofs[blockIdx.x] + v[cur][t] - c;
    start[j] = ex;
    cnt[j] = ex;  // becomes the scatter cursor
    if (j == 0) start[N_N] = E_N;
  }
}

// recs: uint2 { src | I0<<16, q0 | q1<<16 }  (q = 16-bit fixed-point frac)
__global__ __launch_bounds__(256) void scatter_kernel(
    const float* __restrict__ ea, const int* __restrict__ ei,
    int* __restrict__ ofs, uint2* __restrict__ recs) {
  int e = blockIdx.x * 256 + threadIdx.x;
  int s = ei[e];
  int d = ei[E_N + e];
  float2 a = ((const float2*)ea)[e];
  float v0 = a.x * 4.0f, v1 = a.y * 4.0f;
  float b0f = fminf(fmaxf(floorf(v0), 0.0f), 3.0f);
  float b1f = fminf(fmaxf(floorf(v1), 0.0f), 3.0f);
  float f0 = v0 - b0f, f1 = v1 - b1f;
  int I0 = (int)b0f * 5 + (int)b1f;
  unsigned int q0 = (unsigned int)(f0 * 65535.0f + 0.5f);
  unsigned int q1 = (unsigned int)(f1 * 65535.0f + 0.5f);
  int pos = atomicAdd(&ofs[d], 1);
  uint2 rc;
  rc.x = (unsigned int)s | ((unsigned int)I0 << 16);
  rc.y = q0 | (q1 << 16);
  recs[pos] = rc;
}

// ---------------- agg v2: contiguous row-pair loads, 2 VMEM per edge ----------------
// Taps k = {I0, I0+1} and {I0+5, I0+6} are contiguous 256B blocks in Y[node][k][o].
// Lane l<32 covers k=I0(/I0+5), lane l>=32 covers k=I0+1(/I0+6); both halves hold
// channels {2*(l&31), 2*(l&31)+1}. One shfl_xor(32)+add completes each message.
static __device__ __forceinline__ void emsg2(
    const unsigned short* __restrict__ Y, unsigned int rx, unsigned int ry,
    int lane, float gsel, float& mLo, float& mHi) {
  // rx, ry wave-uniform (readfirstlane'd); gsel = (lane<32) ? (1-f1)-style select done by caller
  int src = rx & 0xffff;
  int I0 = rx >> 16;
  float f0 = (float)(ry & 0xffffu) * (1.0f / 65535.0f);
  float f1 = (float)(ry >> 16) * (1.0f / 65535.0f);
  const unsigned* pA = (const unsigned*)(Y + (size_t)src * 1600 + I0 * 64);
  unsigned uA = pA[lane];
  unsigned uB = pA[lane + 160];  // +5 rows = 320 shorts = 160 uints
  float g = (gsel != 0.0f) ? (1.0f - f1) : f1;  // per-half selector
  float wA = (1.0f - f0) * g;
  float wB = f0 * g;
  float aLo = __uint_as_float(uA << 16);
  float aHi = __uint_as_float(uA & 0xffff0000u);
  float bLo = __uint_as_float(uB << 16);
  float bHi = __uint_as_float(uB & 0xffff0000u);
  float pLo = fmaf(wA, aLo, wB * bLo);
  float pHi = fmaf(wA, aHi, wB * bHi);
  mLo = pLo + __shfl_xor(pLo, 32);
  mHi = pHi + __shfl_xor(pHi, 32);
}

__global__ __launch_bounds__(256) void agg_kernel(
    const unsigned short* __restrict__ Y, const uint2* __restrict__ recs,
    const int* __restrict__ start, const float* __restrict__ xin,
    const float* __restrict__ root, const float* __restrict__ bias,
    float* __restrict__ outp, int relu) {
  __shared__ float xl[4][64];
  const int w = threadIdx.x >> 6;
  const int lane = threadIdx.x & 63;
  const int n = blockIdx.x * 4 + w;
  xl[w][lane] = xin[((size_t)n << 6) + lane];
  __syncthreads();

  const int s = __builtin_amdgcn_readfirstlane(start[n]);
  const int e = __builtin_amdgcn_readfirstlane(start[n + 1]);
  const float NI = -__builtin_inff();
  const float gsel = (lane < 32) ? 1.0f : 0.0f;
  float aL0 = NI, aL1 = NI, aL2 = NI, aL3 = NI;
  float aH0 = NI, aH1 = NI, aH2 = NI, aH3 = NI;
  int j = s;
  for (; j + 4 <= e; j += 4) {
    uint2 r0 = recs[j];
    uint2 r1 = recs[j + 1];
    uint2 r2 = recs[j + 2];
    uint2 r3 = recs[j + 3];
    unsigned x0 = __builtin_amdgcn_readfirstlane(r0.x), y0 = __builtin_amdgcn_readfirstlane(r0.y);
    unsigned x1 = __builtin_amdgcn_readfirstlane(r1.x), y1 = __builtin_amdgcn_readfirstlane(r1.y);
    unsigned x2 = __builtin_amdgcn_readfirstlane(r2.x), y2 = __builtin_amdgcn_readfirstlane(r2.y);
    unsigned x3 = __builtin_amdgcn_readfirstlane(r3.x), y3 = __builtin_amdgcn_readfirstlane(r3.y);
    float mL, mH;
    emsg2(Y, x0, y0, lane, gsel, mL, mH);
    aL0 = fmaxf(aL0, mL); aH0 = fmaxf(aH0, mH);
    emsg2(Y, x1, y1, lane, gsel, mL, mH);
    aL1 = fmaxf(aL1, mL); aH1 = fmaxf(aH1, mH);
    emsg2(Y, x2, y2, lane, gsel, mL, mH);
    aL2 = fmaxf(aL2, mL); aH2 = fmaxf(aH2, mH);
    emsg2(Y, x3, y3, lane, gsel, mL, mH);
    aL3 = fmaxf(aL3, mL); aH3 = fmaxf(aH3, mH);
  }
  for (; j < e; ++j) {
    uint2 rc = recs[j];
    unsigned rx = __builtin_amdgcn_readfirstlane(rc.x);
    unsigned ry = __builtin_amdgcn_readfirstlane(rc.y);
    float mL, mH;
    emsg2(Y, rx, ry, lane, gsel, mL, mH);
    aL0 = fmaxf(aL0, mL); aH0 = fmaxf(aH0, mH);
  }
  float accLo = fmaxf(fmaxf(aL0, aL1), fmaxf(aL2, aL3));
  float accHi = fmaxf(fmaxf(aH0, aH1), fmaxf(aH2, aH3));

  // remap: channel c lives at lane c>>1 (Lo if even, Hi if odd; both halves duplicate)
  int m = lane >> 1;
  float vLo = __shfl(accLo, m);
  float vHi = __shfl(accHi, m);
  float acc = (lane & 1) ? vHi : vLo;
  if (s == e) acc = 0.0f;

  float r = bias[lane];
  #pragma unroll 8
  for (int i = 0; i < 64; ++i)
    r += xl[w][i] * root[(i << 6) + lane];
  r += acc;
  if (relu) r = fmaxf(r, 0.0f);
  outp[((size_t)n << 6) + lane] = r;
}

extern "C" void kernel_launch(void* const* d_in, const int* in_sizes, int n_in,
                              void* d_out, int out_size, void* d_ws, size_t ws_size,
                              hipStream_t stream) {
  const float* x = (const float*)d_in[0];
  const int* ei = (const int*)d_in[1];
  const float* ea = (const float*)d_in[2];
  const float* W1 = (const float*)d_in[3];
  const float* root1 = (const float*)d_in[4];
  const float* bias1 = (const float*)d_in[5];
  const float* W2 = (const float*)d_in[6];
  const float* root2 = (const float*)d_in[7];
  const float* bias2 = (const float*)d_in[8];
  float* out = (float*)d_out;

  const size_t yB = (size_t)N_N * 1600 * 2;        // 128,000,000
  const size_t rB = (size_t)E_N * 8;               //   5,120,000
  const size_t sB = (size_t)(N_N + 2) * 4;         //     160,008
  const size_t cB = (size_t)N_N * 4;               //     160,000
  const size_t wB = (size_t)2 * 25 * 64 * 64 * 2;  //     409,600
  const size_t bB = (size_t)1024 * 2;
  if (ws_size < yB + rB + sB + cB + wB + bB) return;

  char* p = (char*)d_ws;
  unsigned short* Y = (unsigned short*)p; p += yB;
  uint2* recs = (uint2*)p;                p += rB;
  int* startA = (int*)p;                  p += sB;
  int* cnt = (int*)p;                     p += cB;   // doubles as scatter cursor
  unsigned short* Wt = (unsigned short*)p; p += wB;  // Wt1 | Wt2
  int* bsum = (int*)p;                    p += 1024;
  int* bofs = (int*)p;
  float* h = out;  // layer-1 output lives in d_out; fully overwritten by layer 2

  unsigned short* Wt1 = Wt;
  unsigned short* Wt2 = Wt + (size_t)25 * 64 * 64;

  dim3 blk(256);

  // ---- CSR build (once, shared by both layers) + both weight transposes ----
  hipMemsetAsync(cnt, 0, cB, stream);
  wtrans_kernel<<<800, blk, 0, stream>>>(W1, W2, Wt);
  hist_kernel<<<E_N / 256, blk, 0, stream>>>(ei, cnt);
  scan1_kernel<<<SCAN_B, blk, 0, stream>>>(cnt, bsum);
  scan2_kernel<<<1, blk, 0, stream>>>(bsum, bofs);
  scan3_kernel<<<SCAN_B, blk, 0, stream>>>(cnt, bofs, startA);
  scatter_kernel<<<E_N / 256, blk, 0, stream>>>(ea, ei, cnt, recs);

  // ---- layer 1 ----
  ygemm_kernel<<<N_N / 64, blk, 0, stream>>>(x, Wt1, Y);
  agg_kernel<<<N_N / 4, blk, 0, stream>>>(Y, recs, startA, x, root1, bias1, h, 1);

  // ---- layer 2 ----
  ygemm_kernel<<<N_N / 64, blk, 0, stream>>>(h, Wt2, Y);
  agg_kernel<<<N_N / 4, blk, 0, stream>>>(Y, recs, startA, h, root2, bias2, out, 0);
}